// Round 2
// baseline (198.375 us; speedup 1.0000x reference)
//
#include <hip/hip_runtime.h>
#include <math.h>

// TTMultiheadAttention simplified:
//   final[b,s,d] = sum_i (1/l_i) * sum_e exp2(cA2_i * g_i[e]) * cr[b,e]
//   g_i[e] = sum_q br[i,e,q] * x[q,s,d]
//   cA2_i  = (sum_k ar[0,k,i]) / sqrt(32) * log2(e)
//   l_i    = sum_e exp2(cA2_i * g_i[e])
//
// Round 1: split the rank axis i across threadIdx.y (block = 256 x 3 = 768
// threads, 12 waves) -> 6144 waves total = 6 waves/SIMD instead of 2.
// Same total FMA count; LDS combine for the 1/l_i-weighted rank sum.
// i is wave-uniform (y-major thread ids), so br row loads stay s_load.

#define SS 512
#define DD 256
#define R2 16
#define R1 3

__global__ __launch_bounds__(768, 6) void tt_attn_kernel(
    const float* __restrict__ x,
    const float* __restrict__ ar,
    const float* __restrict__ br,
    const float* __restrict__ cr,
    float* __restrict__ out)
{
    const int s = blockIdx.x;
    const int d = threadIdx.x;   // 0..255
    const int i = threadIdx.y;   // 0..2 (rank), uniform within each wave

    // +1 pad: combine-read stride 17 words is coprime with 32 banks
    __shared__ float lds_acc[2][DD][R2 + 1];
    __shared__ float lds_l[2][DD];

    const float A = ar[0 * 3 + i] + ar[1 * 3 + i] + ar[2 * 3 + i];
    const float cA2 = A * (0.17677669529663687f * 1.4426950408889634f);

    // v[q] = x[q, s, d]  (coalesced: consecutive d across lanes)
    float v[R2];
#pragma unroll
    for (int q = 0; q < R2; ++q)
        v[q] = x[(q * SS + s) * DD + d];

    float l = 0.f;
    float acc[R2];
#pragma unroll
    for (int b = 0; b < R2; ++b) acc[b] = 0.f;

    const float* bri = br + i * DD * R2;

#pragma unroll 2
    for (int e = 0; e < DD; ++e) {
        const float* brp = bri + e * R2;   // wave-uniform -> s_load_dwordx16
        float g0 = 0.f, g1 = 0.f;          // two independent 8-deep chains
#pragma unroll
        for (int q = 0; q < 8; ++q)  g0 = fmaf(brp[q], v[q], g0);
#pragma unroll
        for (int q = 8; q < 16; ++q) g1 = fmaf(brp[q], v[q], g1);
        const float p = exp2f(cA2 * (g0 + g1));
        l += p;
#pragma unroll
        for (int b = 0; b < R2; ++b)
            acc[b] = fmaf(p, cr[b * DD + e], acc[b]);   // cr uniform -> s_load
    }

    if (i > 0) {
        lds_l[i - 1][d] = l;
#pragma unroll
        for (int b = 0; b < R2; ++b) lds_acc[i - 1][d][b] = acc[b];
    }
    __syncthreads();

    if (i == 0) {
        const float il0 = 1.f / l;
        const float il1 = 1.f / lds_l[0][d];
        const float il2 = 1.f / lds_l[1][d];
#pragma unroll
        for (int b = 0; b < R2; ++b) {
            float o = acc[b] * il0
                    + lds_acc[0][d][b] * il1
                    + lds_acc[1][d][b] * il2;
            out[(b * SS + s) * DD + d] = o;
        }
    }
}

extern "C" void kernel_launch(void* const* d_in, const int* in_sizes, int n_in,
                              void* d_out, int out_size, void* d_ws, size_t ws_size,
                              hipStream_t stream) {
    const float* x  = (const float*)d_in[0];
    const float* ar = (const float*)d_in[1];
    const float* br = (const float*)d_in[2];
    const float* cr = (const float*)d_in[3];
    float* out = (float*)d_out;

    dim3 grid(SS);
    dim3 block(DD, R1);   // 768 threads = 12 waves, i uniform per wave
    hipLaunchKernelGGL(tt_attn_kernel, grid, block, 0, stream, x, ar, br, cr, out);
}

// Round 3
// 100.594 us; speedup vs baseline: 1.9720x; 1.9720x over previous
//
#include <hip/hip_runtime.h>
#include <math.h>

// TTMultiheadAttention simplified:
//   final[b,s,d] = sum_i (1/l_i) * sum_e exp2(g_i[e]) * cr[b,e]
//   g_i[e] = sum_q br_s[i,e,q] * x[q,s,d],  br_s = br * cA2_i (pre-scaled)
//   l_i    = sum_e exp2(g_i[e])
//
// Round 2: kill the scalar-load bottleneck (VALUBusy pinned at 48% in r0/r1):
//   - prep kernel writes cr_t[e][b] (contiguous) and cA2-prescaled br into d_ws
//     -> 4 s_load_dwordx16 per e instead of ~19 scalar loads
//   - e-split x2 across threadIdx.y (block 512 = 8 waves, 4096 waves total),
//     exact partial combine in LDS (l and acc are plain sums over e)
//   - readfirstlane on threadIdx.y so weight addresses provably scalarize

#define SS 512
#define DD 256
#define R2 16
#define R1 3
#define EHALF 128

__global__ void tt_prep(const float* __restrict__ ar,
                        const float* __restrict__ br,
                        const float* __restrict__ cr,
                        float* __restrict__ br_s,
                        float* __restrict__ cr_t)
{
    const int e = blockIdx.x * 64 + threadIdx.x;   // grid 4 x block 64 = 256
    float cA2[R1];
#pragma unroll
    for (int i = 0; i < R1; ++i) {
        float A = ar[0 * R1 + i] + ar[1 * R1 + i] + ar[2 * R1 + i];
        cA2[i] = A * (0.17677669529663687f * 1.4426950408889634f);
    }
#pragma unroll
    for (int i = 0; i < R1; ++i)
#pragma unroll
        for (int q = 0; q < R2; ++q)
            br_s[(i * DD + e) * R2 + q] = br[(i * DD + e) * R2 + q] * cA2[i];
#pragma unroll
    for (int b = 0; b < R2; ++b)
        cr_t[e * R2 + b] = cr[b * DD + e];
}

__global__ __launch_bounds__(512, 4) void tt_attn_kernel(
    const float* __restrict__ x,
    const float* __restrict__ br_s,
    const float* __restrict__ cr_t,
    float* __restrict__ out)
{
    const int s = blockIdx.x;
    const int d = threadIdx.x;                                    // 0..255
    const int h = __builtin_amdgcn_readfirstlane(threadIdx.y);    // 0..1, uniform

    __shared__ float lds[DD][R1 * R2 + R1];   // [256][51], stride 51 (odd)

    // v[q] = x[q, s, d]  (coalesced across lanes)
    float v[R2];
#pragma unroll
    for (int q = 0; q < R2; ++q)
        v[q] = x[(q * SS + s) * DD + d];

    float l[R1] = {0.f, 0.f, 0.f};
    float acc[R1][R2];
#pragma unroll
    for (int i = 0; i < R1; ++i)
#pragma unroll
        for (int b = 0; b < R2; ++b) acc[i][b] = 0.f;

    const int e0 = h * EHALF;
    const float* brh = br_s + e0 * R2;          // rank-i offset added in-loop
    const float* crh = cr_t + e0 * R2;

#pragma unroll 2
    for (int eo = 0; eo < EHALF; ++eo) {
        float p[R1];
#pragma unroll
        for (int i = 0; i < R1; ++i) {
            const float* brp = brh + (i * DD + eo) * R2;  // uniform -> s_load_dwordx16
            float g0 = 0.f, g1 = 0.f;                     // 2 chains of 8 per rank
#pragma unroll
            for (int q = 0; q < 8; ++q)  g0 = fmaf(brp[q], v[q], g0);
#pragma unroll
            for (int q = 8; q < 16; ++q) g1 = fmaf(brp[q], v[q], g1);
            p[i] = exp2f(g0 + g1);
            l[i] += p[i];
        }
        const float* crp = crh + eo * R2;                 // uniform -> s_load_dwordx16
#pragma unroll
        for (int b = 0; b < R2; ++b) {
            float c = crp[b];
#pragma unroll
            for (int i = 0; i < R1; ++i)
                acc[i][b] = fmaf(p[i], c, acc[i][b]);
        }
    }

    if (h == 1) {
#pragma unroll
        for (int i = 0; i < R1; ++i) lds[d][i] = l[i];
#pragma unroll
        for (int i = 0; i < R1; ++i)
#pragma unroll
            for (int b = 0; b < R2; ++b) lds[d][R1 + i * R2 + b] = acc[i][b];
    }
    __syncthreads();

    if (h == 0) {
        float il[R1];
#pragma unroll
        for (int i = 0; i < R1; ++i) il[i] = 1.0f / (l[i] + lds[d][i]);
#pragma unroll
        for (int b = 0; b < R2; ++b) {
            float o = 0.f;
#pragma unroll
            for (int i = 0; i < R1; ++i)
                o += (acc[i][b] + lds[d][R1 + i * R2 + b]) * il[i];
            out[(b * SS + s) * DD + d] = o;
        }
    }
}

extern "C" void kernel_launch(void* const* d_in, const int* in_sizes, int n_in,
                              void* d_out, int out_size, void* d_ws, size_t ws_size,
                              hipStream_t stream) {
    const float* x  = (const float*)d_in[0];
    const float* ar = (const float*)d_in[1];
    const float* br = (const float*)d_in[2];
    const float* cr = (const float*)d_in[3];
    float* out = (float*)d_out;

    float* br_s = (float*)d_ws;                       // 3*256*16*4 = 48 KB
    float* cr_t = (float*)((char*)d_ws + 48 * 1024);  // 256*16*4  = 16 KB

    hipLaunchKernelGGL(tt_prep, dim3(4), dim3(64), 0, stream, ar, br, cr, br_s, cr_t);

    dim3 grid(SS);
    dim3 block(DD, 2);   // 512 threads = 8 waves; y = e-half (wave-uniform)
    hipLaunchKernelGGL(tt_attn_kernel, grid, block, 0, stream, x, br_s, cr_t, out);
}

// Round 4
// 28.776 us; speedup vs baseline: 6.8938x; 3.4958x over previous
//
#include <hip/hip_runtime.h>
#include <hip/hip_bf16.h>
#include <math.h>

// TTMultiheadAttention via MFMA (round 3):
//   per s:  G_i[e,d] = sum_q brs_i[e,q] * x[q,s,d]      (mfma 32x32x16 bf16)
//           P_i = exp2(G_i)   (brs pre-scaled by cA2_i*log2e/sqrt(32))
//           OUT_i[b,d] = sum_e CrT[b,e] * P_i[e,d]      (mfma 32x32x16 bf16,
//                         b rows 0..15 = cr^T, row 16 = ones -> l_i, 17..31 = 0)
//           out[b,s,d] = sum_i OUT_i[b,d] / l_i[d]
// P never leaves registers: C-layout (col=d=lane&31, row=(r&3)+8(r>>2)+4hi)
// -> B-operand layout needs only lane<->lane+32 moves = permlane32_swap.
// No LDS, no syncthreads; each wave owns a 32-wide d tile.

#define SS 512
#define DD 256
#define R2 16
#define NI 3

typedef __attribute__((ext_vector_type(8))) short bf16x8;
typedef __attribute__((ext_vector_type(16))) float f32x16;
typedef __attribute__((ext_vector_type(2))) unsigned uint2v;

union B8 { unsigned w[4]; bf16x8 v; };

static __device__ __forceinline__ unsigned short bf16bits(float f) {
    union { __hip_bfloat16 h; unsigned short u; } c;
    c.h = __float2bfloat16(f);
    return c.u;
}
static __device__ __forceinline__ unsigned packb(float a, float b) {
    union { __hip_bfloat162 h; unsigned u; } c;
    c.h = __float22bfloat162_rn(make_float2(a, b));
    return c.u;
}

// Pre-pack MFMA fragments for br (prescaled, bf16) and cr^T (+ ones row).
// brf[((i*8+et)*64 + l)*8 + j] = bf16(br[i][e = et*32+(l&31)][q = 8*(l>>5)+j] * cA2_i)
// crf[((et*2+h)*64 + l)*8 + j] = b=l&31: b<16 ? bf16(cr[b][e]) : (b==16 ? 1 : 0),
//                                e = et*32 + h*16 + 8*(l>>5) + j
__global__ void tt_prep(const float* __restrict__ ar,
                        const float* __restrict__ br,
                        const float* __restrict__ cr,
                        unsigned short* __restrict__ brf,
                        unsigned short* __restrict__ crf)
{
    const int t = threadIdx.x;  // 256 threads, 1 block
    float cA2[NI];
#pragma unroll
    for (int i = 0; i < NI; ++i) {
        float A = ar[0 * NI + i] + ar[1 * NI + i] + ar[2 * NI + i];
        cA2[i] = A * (0.17677669529663687f * 1.4426950408889634f);
    }
    for (int idx = t; idx < NI * 8 * 64; idx += 256) {
        const int l = idx & 63, et = (idx >> 6) & 7, i = idx >> 9;
        const float* src = br + (i * DD + et * 32 + (l & 31)) * R2 + 8 * (l >> 5);
        const float sc = cA2[i];
#pragma unroll
        for (int j = 0; j < 8; ++j)
            brf[idx * 8 + j] = bf16bits(src[j] * sc);
    }
    for (int idx = t; idx < 8 * 2 * 64; idx += 256) {
        const int l = idx & 63, h = (idx >> 6) & 1, et = idx >> 7;
        const int b = l & 31;
#pragma unroll
        for (int j = 0; j < 8; ++j) {
            const int e = et * 32 + h * 16 + 8 * (l >> 5) + j;
            float v = (b < 16) ? cr[b * DD + e] : (b == 16 ? 1.0f : 0.0f);
            crf[idx * 8 + j] = bf16bits(v);
        }
    }
}

__global__ __launch_bounds__(256, 4) void tt_attn_mfma(
    const float* __restrict__ x,
    const unsigned short* __restrict__ brf,
    const unsigned short* __restrict__ crf,
    float* __restrict__ out)
{
    const int s     = blockIdx.x >> 1;
    const int dhalf = blockIdx.x & 1;
    const int lane  = threadIdx.x & 63;
    const int wv    = threadIdx.x >> 6;
    const int hi    = lane >> 5;
    const int d     = dhalf * 128 + wv * 32 + (lane & 31);

    // x fragment: B-operand of stage 1: lane holds x[q = 8*hi + j][s][d]
    B8 xb;
    const float* xp = x + s * DD + d + (hi ? 8 * SS * DD : 0);
#pragma unroll
    for (int t = 0; t < 4; ++t)
        xb.w[t] = packb(xp[(2 * t) * SS * DD], xp[(2 * t + 1) * SS * DD]);
    const bf16x8 xf = xb.v;

    f32x16 acc0{}, acc1{}, acc2{};
    const f32x16 zf{};

    const unsigned short* brl = brf + lane * 8;
    const unsigned short* crl = crf + lane * 8;

#pragma unroll 1
    for (int et = 0; et < 8; ++et) {
        const bf16x8 crA0 = *(const bf16x8*)(crl + (et * 2 + 0) * 512);
        const bf16x8 crA1 = *(const bf16x8*)(crl + (et * 2 + 1) * 512);
#pragma unroll
        for (int i = 0; i < NI; ++i) {
            const bf16x8 brA = *(const bf16x8*)(brl + (i * 8 + et) * 512);
            f32x16 g = __builtin_amdgcn_mfma_f32_32x32x16_bf16(brA, xf, zf, 0, 0, 0);
            float p[16];
#pragma unroll
            for (int r = 0; r < 16; ++r) p[r] = __builtin_amdgcn_exp2f(g[r]);
            // pack pairs (e rows come 2-consecutive per word)
            const unsigned w01 = packb(p[0],  p[1]);
            const unsigned w23 = packb(p[2],  p[3]);
            const unsigned w45 = packb(p[4],  p[5]);
            const unsigned w67 = packb(p[6],  p[7]);
            const unsigned w89 = packb(p[8],  p[9]);
            const unsigned wAB = packb(p[10], p[11]);
            const unsigned wCD = packb(p[12], p[13]);
            const unsigned wEF = packb(p[14], p[15]);
            // lane<->lane+32 half exchange: one swap fills two B-frag words
            const uint2v s0 = __builtin_amdgcn_permlane32_swap(w01, w45, false, false);
            const uint2v s1 = __builtin_amdgcn_permlane32_swap(w23, w67, false, false);
            const uint2v s2 = __builtin_amdgcn_permlane32_swap(w89, wCD, false, false);
            const uint2v s3 = __builtin_amdgcn_permlane32_swap(wAB, wEF, false, false);
            B8 P0; P0.w[0] = s0.x; P0.w[1] = s1.x; P0.w[2] = s0.y; P0.w[3] = s1.y;
            B8 P1; P1.w[0] = s2.x; P1.w[1] = s3.x; P1.w[2] = s2.y; P1.w[3] = s3.y;
            if (i == 0) {
                acc0 = __builtin_amdgcn_mfma_f32_32x32x16_bf16(crA0, P0.v, acc0, 0, 0, 0);
                acc0 = __builtin_amdgcn_mfma_f32_32x32x16_bf16(crA1, P1.v, acc0, 0, 0, 0);
            } else if (i == 1) {
                acc1 = __builtin_amdgcn_mfma_f32_32x32x16_bf16(crA0, P0.v, acc1, 0, 0, 0);
                acc1 = __builtin_amdgcn_mfma_f32_32x32x16_bf16(crA1, P1.v, acc1, 0, 0, 0);
            } else {
                acc2 = __builtin_amdgcn_mfma_f32_32x32x16_bf16(crA0, P0.v, acc2, 0, 0, 0);
                acc2 = __builtin_amdgcn_mfma_f32_32x32x16_bf16(crA1, P1.v, acc2, 0, 0, 0);
            }
        }
    }

    // l_i sits in C row 16 = reg 8 of hi=0 lanes; broadcast to hi=1 half
    float inv[NI];
#pragma unroll
    for (int i = 0; i < NI; ++i) {
        union { float f; unsigned u; } c;
        c.f = (i == 0) ? acc0[8] : (i == 1) ? acc1[8] : acc2[8];
        const uint2v r = __builtin_amdgcn_permlane32_swap(c.u, c.u, false, false);
        union { unsigned u; float f; } c2; c2.u = r.x;
        inv[i] = 1.0f / c2.f;
    }

#pragma unroll
    for (int r = 0; r < 8; ++r) {
        const int b = (r & 3) + 8 * (r >> 2) + 4 * hi;
        const float o = acc0[r] * inv[0] + acc1[r] * inv[1] + acc2[r] * inv[2];
        out[(b * SS + s) * DD + d] = o;
    }
}

extern "C" void kernel_launch(void* const* d_in, const int* in_sizes, int n_in,
                              void* d_out, int out_size, void* d_ws, size_t ws_size,
                              hipStream_t stream) {
    const float* x  = (const float*)d_in[0];
    const float* ar = (const float*)d_in[1];
    const float* br = (const float*)d_in[2];
    const float* cr = (const float*)d_in[3];
    float* out = (float*)d_out;

    unsigned short* brf = (unsigned short*)d_ws;          // 3*8*64*8 = 12288 ush = 24 KB
    unsigned short* crf = brf + NI * 8 * 64 * 8;          // 8*2*64*8 =  8192 ush = 16 KB

    hipLaunchKernelGGL(tt_prep, dim3(1), dim3(256), 0, stream, ar, br, cr, brf, crf);
    hipLaunchKernelGGL(tt_attn_mfma, dim3(SS * 2), dim3(256), 0, stream,
                       x, brf, crf, out);
}

// Round 5
// 27.651 us; speedup vs baseline: 7.1742x; 1.0407x over previous
//
#include <hip/hip_runtime.h>
#include <hip/hip_bf16.h>
#include <math.h>

// TTMultiheadAttention via MFMA (round 4 = round 3 + LDS weight staging):
//   per s:  G_i[e,d] = sum_q brs_i[e,q] * x[q,s,d]      (mfma 32x32x16 bf16)
//           P_i = exp2(G_i)   (brs pre-scaled by cA2_i*log2e/sqrt(32))
//           OUT_i[b,d] = sum_e CrT[b,e] * P_i[e,d]      (mfma, b row 16 = ones -> l_i)
//           out[b,s,d] = sum_i OUT_i[b,d] / l_i[d]
// Round-4 change: all weight fragments (40 KB) staged block-locally into LDS
// with global_load_lds width=16 (zero VGPR cost), so the hot loop is pure
// ds_read_b128 + MFMA + exp2 -- short-latency and compiler-pipelineable.

#define SS 512
#define DD 256
#define R2 16
#define NI 3

#define BR_USH (NI * 8 * 512)          // 12288 ushorts = 24 KB
#define CR_USH (16 * 512)              // 8192 ushorts = 16 KB
#define WS_USH (BR_USH + CR_USH)       // 20480 ushorts = 40 KB

typedef __attribute__((ext_vector_type(8))) short bf16x8;
typedef __attribute__((ext_vector_type(8))) unsigned short ushort8;
typedef __attribute__((ext_vector_type(16))) float f32x16;
typedef __attribute__((ext_vector_type(2))) unsigned uint2v;

union B8 { unsigned w[4]; bf16x8 v; };

static __device__ __forceinline__ unsigned short bf16bits(float f) {
    union { __hip_bfloat16 h; unsigned short u; } c;
    c.h = __float2bfloat16(f);
    return c.u;
}
static __device__ __forceinline__ unsigned packb(float a, float b) {
    union { __hip_bfloat162 h; unsigned u; } c;
    c.h = __float22bfloat162_rn(make_float2(a, b));
    return c.u;
}

// Fragment packing (one b128 store per thread, 2560 threads = grid 10 x 256):
// brf[((i*8+et)*64 + l)*8 + j] = bf16(br[i][et*32+(l&31)][8*(l>>5)+j] * cA2_i)
// crf[((et*2+h)*64 + l)*8 + j] = b=l&31: b<16 ? cr[b][e] : (b==16 ? 1 : 0),
//                                e = et*32 + h*16 + 8*(l>>5) + j
__global__ void tt_prep(const float* __restrict__ ar,
                        const float* __restrict__ br,
                        const float* __restrict__ cr,
                        unsigned short* __restrict__ wsf)
{
    const int t = blockIdx.x * 256 + threadIdx.x;   // 0..2559
    float cA2[NI];
#pragma unroll
    for (int i = 0; i < NI; ++i) {
        float A = ar[0 * NI + i] + ar[1 * NI + i] + ar[2 * NI + i];
        cA2[i] = A * (0.17677669529663687f * 1.4426950408889634f);
    }
    if (t < NI * 8 * 64) {
        const int l = t & 63, et = (t >> 6) & 7, i = t >> 9;
        const float* src = br + (i * DD + et * 32 + (l & 31)) * R2 + 8 * (l >> 5);
        const float sc = cA2[i];
        ushort8 v;
#pragma unroll
        for (int j = 0; j < 8; ++j) v[j] = bf16bits(src[j] * sc);
        *(ushort8*)(wsf + t * 8) = v;
    } else {
        const int idx = t - NI * 8 * 64;            // 0..1023
        const int l = idx & 63, h = (idx >> 6) & 1, et = idx >> 7;
        const int b = l & 31;
        ushort8 v;
#pragma unroll
        for (int j = 0; j < 8; ++j) {
            const int e = et * 32 + h * 16 + 8 * (l >> 5) + j;
            float val = (b < 16) ? cr[b * DD + e] : (b == 16 ? 1.0f : 0.0f);
            v[j] = bf16bits(val);
        }
        *(ushort8*)(wsf + (BR_USH + idx * 8)) = v;
    }
}

__global__ __launch_bounds__(256, 4) void tt_attn_mfma(
    const float* __restrict__ x,
    const unsigned short* __restrict__ wsf,
    float* __restrict__ out)
{
    __shared__ unsigned short lds[WS_USH];          // 40960 B: 4 blocks/CU = 160 KiB

    const int s     = blockIdx.x >> 1;
    const int dhalf = blockIdx.x & 1;
    const int tid   = threadIdx.x;
    const int lane  = tid & 63;
    const int wv    = tid >> 6;
    const int hi    = lane >> 5;
    const int d     = dhalf * 128 + wv * 32 + (lane & 31);

    // Stage all weight fragments to LDS: 10 chunks x 256 threads x 16 B = 40 KB.
    // LDS dest is wave-uniform base; HW adds lane*16 (linear layout matches).
#pragma unroll
    for (int c = 0; c < 10; ++c) {
        const char* g = (const char*)wsf + (size_t)(c * 256 + tid) * 16;
        char* lp = (char*)lds + (size_t)(c * 256 + wv * 64) * 16;
        __builtin_amdgcn_global_load_lds(
            (const __attribute__((address_space(1))) void*)g,
            (__attribute__((address_space(3))) void*)lp, 16, 0, 0);
    }

    // x fragment (issues while LDS staging is in flight):
    // lane holds x[q = 8*hi + j][s][d]  (B-operand of stage 1)
    B8 xb;
    const float* xp = x + s * DD + d + (hi ? 8 * SS * DD : 0);
#pragma unroll
    for (int t = 0; t < 4; ++t)
        xb.w[t] = packb(xp[(2 * t) * SS * DD], xp[(2 * t + 1) * SS * DD]);
    const bf16x8 xf = xb.v;

    __syncthreads();   // drains vmcnt (global_load_lds) per compiler semantics

    f32x16 acc0{}, acc1{}, acc2{};
    const f32x16 zf{};

    const unsigned short* brl = lds + lane * 8;
    const unsigned short* crl = lds + BR_USH + lane * 8;

#pragma unroll 2
    for (int et = 0; et < 8; ++et) {
        const bf16x8 crA0 = *(const bf16x8*)(crl + (et * 2 + 0) * 512);
        const bf16x8 crA1 = *(const bf16x8*)(crl + (et * 2 + 1) * 512);
#pragma unroll
        for (int i = 0; i < NI; ++i) {
            const bf16x8 brA = *(const bf16x8*)(brl + (i * 8 + et) * 512);
            f32x16 g = __builtin_amdgcn_mfma_f32_32x32x16_bf16(brA, xf, zf, 0, 0, 0);
            float p[16];
#pragma unroll
            for (int r = 0; r < 16; ++r) p[r] = __builtin_amdgcn_exp2f(g[r]);
            const unsigned w01 = packb(p[0],  p[1]);
            const unsigned w23 = packb(p[2],  p[3]);
            const unsigned w45 = packb(p[4],  p[5]);
            const unsigned w67 = packb(p[6],  p[7]);
            const unsigned w89 = packb(p[8],  p[9]);
            const unsigned wAB = packb(p[10], p[11]);
            const unsigned wCD = packb(p[12], p[13]);
            const unsigned wEF = packb(p[14], p[15]);
            // lane<->lane+32 half exchange: one swap fills two B-frag words
            const uint2v s0 = __builtin_amdgcn_permlane32_swap(w01, w45, false, false);
            const uint2v s1 = __builtin_amdgcn_permlane32_swap(w23, w67, false, false);
            const uint2v s2 = __builtin_amdgcn_permlane32_swap(w89, wCD, false, false);
            const uint2v s3 = __builtin_amdgcn_permlane32_swap(wAB, wEF, false, false);
            B8 P0; P0.w[0] = s0.x; P0.w[1] = s1.x; P0.w[2] = s0.y; P0.w[3] = s1.y;
            B8 P1; P1.w[0] = s2.x; P1.w[1] = s3.x; P1.w[2] = s2.y; P1.w[3] = s3.y;
            if (i == 0) {
                acc0 = __builtin_amdgcn_mfma_f32_32x32x16_bf16(crA0, P0.v, acc0, 0, 0, 0);
                acc0 = __builtin_amdgcn_mfma_f32_32x32x16_bf16(crA1, P1.v, acc0, 0, 0, 0);
            } else if (i == 1) {
                acc1 = __builtin_amdgcn_mfma_f32_32x32x16_bf16(crA0, P0.v, acc1, 0, 0, 0);
                acc1 = __builtin_amdgcn_mfma_f32_32x32x16_bf16(crA1, P1.v, acc1, 0, 0, 0);
            } else {
                acc2 = __builtin_amdgcn_mfma_f32_32x32x16_bf16(crA0, P0.v, acc2, 0, 0, 0);
                acc2 = __builtin_amdgcn_mfma_f32_32x32x16_bf16(crA1, P1.v, acc2, 0, 0, 0);
            }
        }
    }

    // l_i sits in C row 16 = reg 8 of hi=0 lanes; broadcast to hi=1 half
    float inv[NI];
#pragma unroll
    for (int i = 0; i < NI; ++i) {
        union { float f; unsigned u; } c;
        c.f = (i == 0) ? acc0[8] : (i == 1) ? acc1[8] : acc2[8];
        const uint2v r = __builtin_amdgcn_permlane32_swap(c.u, c.u, false, false);
        union { unsigned u; float f; } c2; c2.u = r.x;
        inv[i] = 1.0f / c2.f;
    }

#pragma unroll
    for (int r = 0; r < 8; ++r) {
        const int b = (r & 3) + 8 * (r >> 2) + 4 * hi;
        const float o = acc0[r] * inv[0] + acc1[r] * inv[1] + acc2[r] * inv[2];
        out[(b * SS + s) * DD + d] = o;
    }
}

extern "C" void kernel_launch(void* const* d_in, const int* in_sizes, int n_in,
                              void* d_out, int out_size, void* d_ws, size_t ws_size,
                              hipStream_t stream) {
    const float* x  = (const float*)d_in[0];
    const float* ar = (const float*)d_in[1];
    const float* br = (const float*)d_in[2];
    const float* cr = (const float*)d_in[3];
    float* out = (float*)d_out;

    unsigned short* wsf = (unsigned short*)d_ws;   // 40 KB: brf (24K) then crf (16K)

    hipLaunchKernelGGL(tt_prep, dim3(10), dim3(256), 0, stream, ar, br, cr, wsf);
    hipLaunchKernelGGL(tt_attn_mfma, dim3(SS * 2), dim3(256), 0, stream, x, wsf, out);
}